// Round 5
// baseline (2619.244 us; speedup 1.0000x reference)
//
#include <hip/hip_runtime.h>

#define NN 100000
#define NE 1600000
#define DIN 128
#define HD 64
#define NBUK 1563          // ceil(100000/64) buckets of 64 nodes
#define EPB 2560           // edges per block in bucket build
#define NBLK 625           // 625 * 2560 = 1,600,000
#define STRIDE 1536        // fixed bucket capacity (mean 1024, sigma 32 -> 16 sigma margin)

typedef __attribute__((ext_vector_type(8))) short bf16x8;
typedef __attribute__((ext_vector_type(4))) float f32x4;

__device__ __forceinline__ unsigned short f2bf(float f) {
    unsigned int u = __float_as_uint(f);
    u += 0x7fff + ((u >> 16) & 1);     // round-to-nearest-even
    return (unsigned short)(u >> 16);
}
__device__ __forceinline__ float bf2f(unsigned int lo16) {
    return __uint_as_float(lo16 << 16);
}

// ---------------- weight prep: bf16 transposed tables Wt[n][k] ----------------
__global__ __launch_bounds__(256) void k_wprep(const float* __restrict__ pW, const float* __restrict__ W1,
                                               const float* __restrict__ W2,
                                               unsigned short* __restrict__ pWt,
                                               unsigned short* __restrict__ W1t,
                                               unsigned short* __restrict__ W2t) {
    int idx = blockIdx.x * 256 + threadIdx.x;   // 80*256 = 20480
    if (idx < 8192) {
        int n = idx >> 7, k = idx & 127;
        pWt[idx] = f2bf(pW[k * 64 + n]);
    } else if (idx < 16384) {
        int j = idx - 8192;
        int n = j >> 7, k = j & 127;
        W1t[j] = f2bf(W1[k * 64 + n]);
    } else {
        int j = idx - 16384;
        int n = j >> 6, k = j & 63;
        W2t[j] = f2bf(W2[k * 64 + n]);
    }
}

// ---------------- front: MFMA projmlp (0..NBUK-1) || bscatter (next NBLK) || mprep (last 64) ----------------
// Round-0 frozen form (measured 95.8-100 us). Do not touch.
__global__ __launch_bounds__(256) void k_front(const float* __restrict__ x,
        const unsigned short* __restrict__ pWt, const float* __restrict__ pb,
        const unsigned short* __restrict__ W1t, const float* __restrict__ b1,
        const float* __restrict__ g1, const float* __restrict__ be1,
        const unsigned short* __restrict__ W2t, const float* __restrict__ b2,
        const float* __restrict__ g2, const float* __restrict__ be2,
        const float* __restrict__ w3, const float* __restrict__ b3,
        unsigned short* __restrict__ h0b, float* __restrict__ out,
        const int* __restrict__ src, const int* __restrict__ dst, const float* __restrict__ ew,
        int* __restrict__ cnt, int2* __restrict__ ep,
        const float* __restrict__ gw, float* __restrict__ M, float4 th) {
    __shared__ int shmem[2 * NBUK];               // 12504 B; projmlp aliases first 8 KB as bf16 m1s
    unsigned short* m1s = (unsigned short*)shmem;
    int tid = threadIdx.x;
    int bb = blockIdx.x;

    if (bb >= NBUK) {
        if (bb < NBUK + NBLK) {
            // ---- bscatter ----
            int* lh = shmem;
            int* gb = shmem + NBUK;
            for (int b = tid; b < NBUK; b += 256) lh[b] = 0;
            __syncthreads();
            int base = (bb - NBUK) * EPB + tid;
#pragma unroll
            for (int i = 0; i < EPB / 256; ++i)
                atomicAdd(&lh[dst[base + i * 256] >> 6], 1);
            __syncthreads();
            for (int b = tid; b < NBUK; b += 256) {
                int c = lh[b];
                if (c) gb[b] = atomicAdd(&cnt[b], c);
            }
            __syncthreads();
#pragma unroll
            for (int i = 0; i < EPB / 256; ++i) {
                int e = base + i * 256;
                int d = dst[e];
                int b = d >> 6;
                int pos = atomicAdd(&gb[b], 1);
                ep[(size_t)b * STRIDE + pos] = make_int2(src[e] | ((d & 63) << 17),
                                                         __float_as_int(0.9f * ew[e]));
            }
        } else {
            // ---- mprep ----
            int idx = (bb - NBUK - NBLK) * 256 + tid;   // < 4*64*64
            int l = idx >> 12;
            int k = (idx >> 6) & 63;
            int c = idx & 63;
            float theta = (l == 0) ? th.x : (l == 1) ? th.y : (l == 2) ? th.z : th.w;
            float m = theta * gw[idx];
            if (k == c) m += (1.f - theta);
            M[idx] = m;
        }
        return;
    }

    // ---- projmlp (MFMA) ----
    int w = tid >> 6, lane = tid & 63;
    int n16 = lane & 15, quad = lane >> 4;
    int tile0 = bb * 64;
    int rowA = tile0 + w * 16 + n16;
    bool rvalid = rowA < NN;

    bf16x8 afr[4];
#pragma unroll
    for (int c = 0; c < 4; ++c) {
        float4 xa = make_float4(0.f, 0.f, 0.f, 0.f), xb = xa;
        if (rvalid) {
            const float* px = &x[(size_t)rowA * DIN + c * 32 + quad * 8];
            xa = *(const float4*)px;
            xb = *(const float4*)(px + 4);
        }
        afr[c][0] = (short)f2bf(xa.x); afr[c][1] = (short)f2bf(xa.y);
        afr[c][2] = (short)f2bf(xa.z); afr[c][3] = (short)f2bf(xa.w);
        afr[c][4] = (short)f2bf(xb.x); afr[c][5] = (short)f2bf(xb.y);
        afr[c][6] = (short)f2bf(xb.z); afr[c][7] = (short)f2bf(xb.w);
    }

    f32x4 accP[4] = {{0.f, 0.f, 0.f, 0.f}, {0.f, 0.f, 0.f, 0.f}, {0.f, 0.f, 0.f, 0.f}, {0.f, 0.f, 0.f, 0.f}};
    f32x4 accM[4] = {{0.f, 0.f, 0.f, 0.f}, {0.f, 0.f, 0.f, 0.f}, {0.f, 0.f, 0.f, 0.f}, {0.f, 0.f, 0.f, 0.f}};
#pragma unroll
    for (int c = 0; c < 4; ++c) {
#pragma unroll
        for (int t = 0; t < 4; ++t) {
            bf16x8 bp = *(const bf16x8*)&pWt[(size_t)(t * 16 + n16) * 128 + c * 32 + quad * 8];
            bf16x8 bm = *(const bf16x8*)&W1t[(size_t)(t * 16 + n16) * 128 + c * 32 + quad * 8];
            accP[t] = __builtin_amdgcn_mfma_f32_16x16x32_bf16(afr[c], bp, accP[t], 0, 0, 0);
            accM[t] = __builtin_amdgcn_mfma_f32_16x16x32_bf16(afr[c], bm, accM[t], 0, 0, 0);
        }
    }

    // D layout: col = t*16 + n16, row = w*16 + quad*4 + reg
#pragma unroll
    for (int r = 0; r < 4; ++r) {
        int gn = tile0 + w * 16 + quad * 4 + r;
        if (gn < NN) {
#pragma unroll
            for (int t = 0; t < 4; ++t) {
                int col = t * 16 + n16;
                h0b[(size_t)gn * 64 + col] = f2bf(accP[t][r] + pb[col]);
            }
        }
    }

    float vals1[4][4];
    float mu_[4], rs_[4];
#pragma unroll
    for (int r = 0; r < 4; ++r) {
        float s = 0.f, q = 0.f;
#pragma unroll
        for (int t = 0; t < 4; ++t) {
            float v = accM[t][r] + b1[t * 16 + n16];
            vals1[r][t] = v; s += v; q += v * v;
        }
#pragma unroll
        for (int m = 1; m < 16; m <<= 1) { s += __shfl_xor(s, m); q += __shfl_xor(q, m); }
        float mu = s * (1.f / 64.f);
        float var = q * (1.f / 64.f) - mu * mu;
        mu_[r] = mu; rs_[r] = rsqrtf(var + 1e-5f);
    }
#pragma unroll
    for (int r = 0; r < 4; ++r) {
#pragma unroll
        for (int t = 0; t < 4; ++t) {
            int col = t * 16 + n16;
            float m = (vals1[r][t] - mu_[r]) * rs_[r] * g1[col] + be1[col];
            m1s[w * 1024 + (quad * 4 + r) * 64 + col] = f2bf(fmaxf(m, 0.f));
        }
    }
    __syncthreads();

    bf16x8 a2[2];
#pragma unroll
    for (int c = 0; c < 2; ++c)
        a2[c] = *(const bf16x8*)&m1s[w * 1024 + n16 * 64 + c * 32 + quad * 8];
    f32x4 acc2[4] = {{0.f, 0.f, 0.f, 0.f}, {0.f, 0.f, 0.f, 0.f}, {0.f, 0.f, 0.f, 0.f}, {0.f, 0.f, 0.f, 0.f}};
#pragma unroll
    for (int c = 0; c < 2; ++c) {
#pragma unroll
        for (int t = 0; t < 4; ++t) {
            bf16x8 b4 = *(const bf16x8*)&W2t[(size_t)(t * 16 + n16) * 64 + c * 32 + quad * 8];
            acc2[t] = __builtin_amdgcn_mfma_f32_16x16x32_bf16(a2[c], b4, acc2[t], 0, 0, 0);
        }
    }

#pragma unroll
    for (int r = 0; r < 4; ++r) {
        float s = 0.f, q = 0.f;
        float vr[4];
#pragma unroll
        for (int t = 0; t < 4; ++t) {
            float v = acc2[t][r] + b2[t * 16 + n16];
            vr[t] = v; s += v; q += v * v;
        }
#pragma unroll
        for (int m = 1; m < 16; m <<= 1) { s += __shfl_xor(s, m); q += __shfl_xor(q, m); }
        float mu = s * (1.f / 64.f);
        float var = q * (1.f / 64.f) - mu * mu;
        float rs = rsqrtf(var + 1e-5f);
        float p = 0.f;
#pragma unroll
        for (int t = 0; t < 4; ++t) {
            int col = t * 16 + n16;
            float m = fmaxf((vr[t] - mu) * rs * g2[col] + be2[col], 0.f);
            p += m * w3[col];
        }
#pragma unroll
        for (int m = 1; m < 16; m <<= 1) p += __shfl_xor(p, m);
        if (n16 == 0) {
            int gn = tile0 + w * 16 + quad * 4 + r;
            if (gn < NN) out[gn] = 0.5f * (p + b3[0]);
        }
    }
}

// ---------------- unsorted-bucket accumulate: As[loc] += w * h[src] via LDS f32 atomics ----------------
// 16 lanes per edge (hl covers the 128B row), 16 edge slots per 256-thread block, 2-deep batch.
__device__ __forceinline__ void bucket_accum(const int2* __restrict__ ep, size_t base, int cntb,
                                             const unsigned short* __restrict__ hbin,
                                             float* __restrict__ As, int slot, int hl) {
    for (int e0 = 0; e0 < cntb; e0 += 32) {
        int eA = e0 + slot;
        int eB = eA + 16;
        bool vA = eA < cntb, vB = eB < cntb;
        int2 mA = make_int2(0, 0), mB = make_int2(0, 0);
        if (vA) mA = ep[base + eA];
        if (vB) mB = ep[base + eB];
        uint2 pA = make_uint2(0u, 0u), pB = make_uint2(0u, 0u);
        if (vA) pA = *(const uint2*)&hbin[(size_t)(mA.x & 0x1FFFF) * 64 + hl * 4];
        if (vB) pB = *(const uint2*)&hbin[(size_t)(mB.x & 0x1FFFF) * 64 + hl * 4];
        if (vA) {
            float w = __int_as_float(mA.y);
            float* d = &As[((mA.x >> 17) & 63) * 65 + hl * 4];
            atomicAdd(d + 0, w * bf2f(pA.x & 0xffffu));
            atomicAdd(d + 1, w * bf2f(pA.x >> 16));
            atomicAdd(d + 2, w * bf2f(pA.y & 0xffffu));
            atomicAdd(d + 3, w * bf2f(pA.y >> 16));
        }
        if (vB) {
            float w = __int_as_float(mB.y);
            float* d = &As[((mB.x >> 17) & 63) * 65 + hl * 4];
            atomicAdd(d + 0, w * bf2f(pB.x & 0xffffu));
            atomicAdd(d + 1, w * bf2f(pB.x >> 16));
            atomicAdd(d + 2, w * bf2f(pB.y & 0xffffu));
            atomicAdd(d + 3, w * bf2f(pB.y >> 16));
        }
    }
}

// ---------------- layers 1..3: block = bucket (64 rows), unsorted edges, no sort/rp/ep2 ----------------
__global__ __launch_bounds__(256) void k_layer(const int2* __restrict__ ep, const int* __restrict__ cnt,
                                               const unsigned short* __restrict__ hbin,
                                               const unsigned short* __restrict__ h0b,
                                               const float* __restrict__ M,
                                               unsigned short* __restrict__ hbout) {
    __shared__ float As[64 * 65];
    int tid = threadIdx.x;
    int b = blockIdx.x;
    int tile0 = b * 64;
    size_t base = (size_t)b * STRIDE;
    int cntb = cnt[b];

    // init As = 0.1 * h0 (self/alpha term); invalid rows -> 0
#pragma unroll
    for (int t = 0; t < 4; ++t) {
        int s = t * 256 + tid;                // s < 1024 = 64 rows * 16 col-groups
        int r = s >> 4, h = s & 15;
        int node = tile0 + r;
        float v0 = 0.f, v1 = 0.f, v2 = 0.f, v3 = 0.f;
        if (node < NN) {
            uint2 hv = *(const uint2*)&h0b[(size_t)node * 64 + h * 4];
            v0 = 0.1f * bf2f(hv.x & 0xffffu); v1 = 0.1f * bf2f(hv.x >> 16);
            v2 = 0.1f * bf2f(hv.y & 0xffffu); v3 = 0.1f * bf2f(hv.y >> 16);
        }
        As[r * 65 + h * 4 + 0] = v0;
        As[r * 65 + h * 4 + 1] = v1;
        As[r * 65 + h * 4 + 2] = v2;
        As[r * 65 + h * 4 + 3] = v3;
    }
    __syncthreads();

    bucket_accum(ep, base, cntb, hbin, As, tid >> 4, tid & 15);
    __syncthreads();

    int cc = tid & 15, nc = tid >> 4;
    float acc[4][4] = {{0.f}};
#pragma unroll 8
    for (int k = 0; k < 64; ++k) {
        float4 b4 = *(const float4*)&M[k * 64 + cc * 4];
        float a0x = As[(nc * 4 + 0) * 65 + k];
        float a1x = As[(nc * 4 + 1) * 65 + k];
        float a2x = As[(nc * 4 + 2) * 65 + k];
        float a3x = As[(nc * 4 + 3) * 65 + k];
        acc[0][0] += a0x * b4.x; acc[0][1] += a0x * b4.y; acc[0][2] += a0x * b4.z; acc[0][3] += a0x * b4.w;
        acc[1][0] += a1x * b4.x; acc[1][1] += a1x * b4.y; acc[1][2] += a1x * b4.z; acc[1][3] += a1x * b4.w;
        acc[2][0] += a2x * b4.x; acc[2][1] += a2x * b4.y; acc[2][2] += a2x * b4.z; acc[2][3] += a2x * b4.w;
        acc[3][0] += a3x * b4.x; acc[3][1] += a3x * b4.y; acc[3][2] += a3x * b4.z; acc[3][3] += a3x * b4.w;
    }
#pragma unroll
    for (int i = 0; i < 4; ++i) {
        int gn = tile0 + nc * 4 + i;
        if (gn >= NN) continue;
        ushort4 ob;
        ob.x = f2bf(fmaxf(acc[i][0], 0.f));
        ob.y = f2bf(fmaxf(acc[i][1], 0.f));
        ob.z = f2bf(fmaxf(acc[i][2], 0.f));
        ob.w = f2bf(fmaxf(acc[i][3], 0.f));
        *(ushort4*)&hbout[(size_t)gn * 64 + cc * 4] = ob;
    }
}

// ---------------- layer 4 + folded JK-max/head: out += 0.5*(max(h1..h4) @ hw + hb) ----------------
__global__ __launch_bounds__(256) void k_layer4(const int2* __restrict__ ep, const int* __restrict__ cnt,
                                                const unsigned short* __restrict__ hbin,   // h3
                                                const unsigned short* __restrict__ h0b,
                                                const float* __restrict__ M,
                                                const unsigned short* __restrict__ h1,
                                                const unsigned short* __restrict__ h2,
                                                const unsigned short* __restrict__ h3,
                                                const float* __restrict__ hw,
                                                const float* __restrict__ hbias,
                                                float* __restrict__ out) {
    __shared__ float As[64 * 65];
    int tid = threadIdx.x;
    int b = blockIdx.x;
    int tile0 = b * 64;
    size_t base = (size_t)b * STRIDE;
    int cntb = cnt[b];

#pragma unroll
    for (int t = 0; t < 4; ++t) {
        int s = t * 256 + tid;
        int r = s >> 4, h = s & 15;
        int node = tile0 + r;
        float v0 = 0.f, v1 = 0.f, v2 = 0.f, v3 = 0.f;
        if (node < NN) {
            uint2 hv = *(const uint2*)&h0b[(size_t)node * 64 + h * 4];
            v0 = 0.1f * bf2f(hv.x & 0xffffu); v1 = 0.1f * bf2f(hv.x >> 16);
            v2 = 0.1f * bf2f(hv.y & 0xffffu); v3 = 0.1f * bf2f(hv.y >> 16);
        }
        As[r * 65 + h * 4 + 0] = v0;
        As[r * 65 + h * 4 + 1] = v1;
        As[r * 65 + h * 4 + 2] = v2;
        As[r * 65 + h * 4 + 3] = v3;
    }
    __syncthreads();

    bucket_accum(ep, base, cntb, hbin, As, tid >> 4, tid & 15);
    __syncthreads();

    int cc = tid & 15, nc = tid >> 4;
    float acc[4][4] = {{0.f}};
#pragma unroll 8
    for (int k = 0; k < 64; ++k) {
        float4 b4 = *(const float4*)&M[k * 64 + cc * 4];
        float a0x = As[(nc * 4 + 0) * 65 + k];
        float a1x = As[(nc * 4 + 1) * 65 + k];
        float a2x = As[(nc * 4 + 2) * 65 + k];
        float a3x = As[(nc * 4 + 3) * 65 + k];
        acc[0][0] += a0x * b4.x; acc[0][1] += a0x * b4.y; acc[0][2] += a0x * b4.z; acc[0][3] += a0x * b4.w;
        acc[1][0] += a1x * b4.x; acc[1][1] += a1x * b4.y; acc[1][2] += a1x * b4.z; acc[1][3] += a1x * b4.w;
        acc[2][0] += a2x * b4.x; acc[2][1] += a2x * b4.y; acc[2][2] += a2x * b4.z; acc[2][3] += a2x * b4.w;
        acc[3][0] += a3x * b4.x; acc[3][1] += a3x * b4.y; acc[3][2] += a3x * b4.z; acc[3][3] += a3x * b4.w;
    }
    float hw4[4];
#pragma unroll
    for (int j = 0; j < 4; ++j) hw4[j] = hw[cc * 4 + j];
#pragma unroll
    for (int i = 0; i < 4; ++i) {
        int gn = tile0 + nc * 4 + i;
        float p = 0.f;
        if (gn < NN) {
            size_t q = (size_t)gn * 64 + cc * 4;
            uint2 v1 = *(const uint2*)&h1[q];
            uint2 v2 = *(const uint2*)&h2[q];
            uint2 v3 = *(const uint2*)&h3[q];
            float m0 = fmaxf(acc[i][0], 0.f);
            float m1 = fmaxf(acc[i][1], 0.f);
            float m2 = fmaxf(acc[i][2], 0.f);
            float m3 = fmaxf(acc[i][3], 0.f);
            m0 = fmaxf(m0, fmaxf(bf2f(v1.x & 0xffffu), fmaxf(bf2f(v2.x & 0xffffu), bf2f(v3.x & 0xffffu))));
            m1 = fmaxf(m1, fmaxf(bf2f(v1.x >> 16), fmaxf(bf2f(v2.x >> 16), bf2f(v3.x >> 16))));
            m2 = fmaxf(m2, fmaxf(bf2f(v1.y & 0xffffu), fmaxf(bf2f(v2.y & 0xffffu), bf2f(v3.y & 0xffffu))));
            m3 = fmaxf(m3, fmaxf(bf2f(v1.y >> 16), fmaxf(bf2f(v2.y >> 16), bf2f(v3.y >> 16))));
            p = m0 * hw4[0] + m1 * hw4[1] + m2 * hw4[2] + m3 * hw4[3];
        }
#pragma unroll
        for (int m = 1; m < 16; m <<= 1) p += __shfl_xor(p, m);
        if (cc == 0 && gn < NN) out[gn] = out[gn] + 0.5f * (p + hbias[0]);
    }
}

extern "C" void kernel_launch(void* const* d_in, const int* in_sizes, int n_in,
                              void* d_out, int out_size, void* d_ws, size_t ws_size,
                              hipStream_t stream) {
    const float* x      = (const float*)d_in[0];
    const float* ew     = (const float*)d_in[1];
    const float* proj_w = (const float*)d_in[2];
    const float* proj_b = (const float*)d_in[3];
    const float* gcn_w  = (const float*)d_in[4];
    const float* w1     = (const float*)d_in[5];
    const float* b1     = (const float*)d_in[6];
    const float* g1     = (const float*)d_in[7];
    const float* be1    = (const float*)d_in[8];
    const float* w2     = (const float*)d_in[9];
    const float* b2     = (const float*)d_in[10];
    const float* g2     = (const float*)d_in[11];
    const float* be2    = (const float*)d_in[12];
    const float* w3     = (const float*)d_in[13];
    const float* b3     = (const float*)d_in[14];
    const float* hw     = (const float*)d_in[15];
    const float* hb     = (const float*)d_in[16];
    const int*   ei     = (const int*)d_in[17];
    float* out = (float*)d_out;

    char* ws = (char*)d_ws;
    size_t off = 0;
    auto alloc = [&](size_t bytes) { size_t o = off; off += (bytes + 255) & ~(size_t)255; return o; };
    unsigned short* h0b = (unsigned short*)(ws + alloc((size_t)NN * 64 * 2));
    unsigned short* hl1 = (unsigned short*)(ws + alloc((size_t)NN * 64 * 2));
    unsigned short* hl2 = (unsigned short*)(ws + alloc((size_t)NN * 64 * 2));
    unsigned short* hl3 = (unsigned short*)(ws + alloc((size_t)NN * 64 * 2));
    float* M       = (float*)(ws + alloc((size_t)4 * 64 * 64 * 4));
    unsigned short* pWt = (unsigned short*)(ws + alloc((size_t)8192 * 2));
    unsigned short* W1t = (unsigned short*)(ws + alloc((size_t)8192 * 2));
    unsigned short* W2t = (unsigned short*)(ws + alloc((size_t)4096 * 2));
    int*   cnt     = (int*)(ws + alloc((size_t)NBUK * 4));
    int2*  ep      = (int2*)(ws + alloc((size_t)NBUK * STRIDE * 8));

    const int* srcv = ei;
    const int* dstv = ei + NE;

    hipMemsetAsync(cnt, 0, (size_t)NBUK * 4, stream);

    k_wprep<<<80, 256, 0, stream>>>(proj_w, w1, w2, pWt, W1t, W2t);

    // front: MFMA projmlp || bscatter || mprep  (theta_l = log(1/(l+1) + 1))
    k_front<<<NBUK + NBLK + 64, 256, 0, stream>>>(x, pWt, proj_b, W1t, b1, g1, be1,
        W2t, b2, g2, be2, w3, b3, h0b, out, srcv, dstv, ew, cnt, ep, gcn_w, M,
        make_float4(0.69314718055994531f, 0.40546510810816438f,
                    0.28768207245178085f, 0.22314355131420976f));

    k_layer<<<NBUK, 256, 0, stream>>>(ep, cnt, h0b, h0b, M + 0 * 4096, hl1);
    k_layer<<<NBUK, 256, 0, stream>>>(ep, cnt, hl1, h0b, M + 1 * 4096, hl2);
    k_layer<<<NBUK, 256, 0, stream>>>(ep, cnt, hl2, h0b, M + 2 * 4096, hl3);
    k_layer4<<<NBUK, 256, 0, stream>>>(ep, cnt, hl3, h0b, M + 3 * 4096,
                                       hl1, hl2, hl3, hw, hb, out);
}

// Round 6
// 417.744 us; speedup vs baseline: 6.2700x; 6.2700x over previous
//
#include <hip/hip_runtime.h>

#define NN 100000
#define NE 1600000
#define DIN 128
#define HD 64
#define NBUK 1563          // ceil(100000/64) buckets of 64 nodes
#define EPB 2560           // edges per block in bucket build
#define NBLK 625           // 625 * 2560 = 1,600,000
#define STRIDE 1536        // fixed bucket capacity (mean 1024, sigma 32 -> 16 sigma margin)

typedef __attribute__((ext_vector_type(8))) short bf16x8;
typedef __attribute__((ext_vector_type(4))) float f32x4;

__device__ __forceinline__ unsigned short f2bf(float f) {
    unsigned int u = __float_as_uint(f);
    u += 0x7fff + ((u >> 16) & 1);     // round-to-nearest-even
    return (unsigned short)(u >> 16);
}
__device__ __forceinline__ float bf2f(unsigned int lo16) {
    return __uint_as_float(lo16 << 16);
}

// ---------------- weight prep: bf16 transposed tables Wt[n][k] ----------------
__global__ __launch_bounds__(256) void k_wprep(const float* __restrict__ pW, const float* __restrict__ W1,
                                               const float* __restrict__ W2,
                                               unsigned short* __restrict__ pWt,
                                               unsigned short* __restrict__ W1t,
                                               unsigned short* __restrict__ W2t) {
    int idx = blockIdx.x * 256 + threadIdx.x;   // 80*256 = 20480
    if (idx < 8192) {
        int n = idx >> 7, k = idx & 127;
        pWt[idx] = f2bf(pW[k * 64 + n]);
    } else if (idx < 16384) {
        int j = idx - 8192;
        int n = j >> 7, k = j & 127;
        W1t[j] = f2bf(W1[k * 64 + n]);
    } else {
        int j = idx - 16384;
        int n = j >> 6, k = j & 63;
        W2t[j] = f2bf(W2[k * 64 + n]);
    }
}

// ---------------- front: MFMA projmlp (0..NBUK-1) || bscatter (next NBLK) || mprep (last 64) ----------------
// Round-0 frozen form (measured 95.8-100 us). Do not touch.
__global__ __launch_bounds__(256) void k_front(const float* __restrict__ x,
        const unsigned short* __restrict__ pWt, const float* __restrict__ pb,
        const unsigned short* __restrict__ W1t, const float* __restrict__ b1,
        const float* __restrict__ g1, const float* __restrict__ be1,
        const unsigned short* __restrict__ W2t, const float* __restrict__ b2,
        const float* __restrict__ g2, const float* __restrict__ be2,
        const float* __restrict__ w3, const float* __restrict__ b3,
        unsigned short* __restrict__ h0b, float* __restrict__ out,
        const int* __restrict__ src, const int* __restrict__ dst, const float* __restrict__ ew,
        int* __restrict__ cnt, int2* __restrict__ ep,
        const float* __restrict__ gw, float* __restrict__ M, float4 th) {
    __shared__ int shmem[2 * NBUK];               // 12504 B; projmlp aliases first 8 KB as bf16 m1s
    unsigned short* m1s = (unsigned short*)shmem;
    int tid = threadIdx.x;
    int bb = blockIdx.x;

    if (bb >= NBUK) {
        if (bb < NBUK + NBLK) {
            // ---- bscatter ----
            int* lh = shmem;
            int* gb = shmem + NBUK;
            for (int b = tid; b < NBUK; b += 256) lh[b] = 0;
            __syncthreads();
            int base = (bb - NBUK) * EPB + tid;
#pragma unroll
            for (int i = 0; i < EPB / 256; ++i)
                atomicAdd(&lh[dst[base + i * 256] >> 6], 1);
            __syncthreads();
            for (int b = tid; b < NBUK; b += 256) {
                int c = lh[b];
                if (c) gb[b] = atomicAdd(&cnt[b], c);
            }
            __syncthreads();
#pragma unroll
            for (int i = 0; i < EPB / 256; ++i) {
                int e = base + i * 256;
                int d = dst[e];
                int b = d >> 6;
                int pos = atomicAdd(&gb[b], 1);
                ep[(size_t)b * STRIDE + pos] = make_int2(src[e] | ((d & 63) << 17),
                                                         __float_as_int(0.9f * ew[e]));
            }
        } else {
            // ---- mprep ----
            int idx = (bb - NBUK - NBLK) * 256 + tid;   // < 4*64*64
            int l = idx >> 12;
            int k = (idx >> 6) & 63;
            int c = idx & 63;
            float theta = (l == 0) ? th.x : (l == 1) ? th.y : (l == 2) ? th.z : th.w;
            float m = theta * gw[idx];
            if (k == c) m += (1.f - theta);
            M[idx] = m;
        }
        return;
    }

    // ---- projmlp (MFMA) ----
    int w = tid >> 6, lane = tid & 63;
    int n16 = lane & 15, quad = lane >> 4;
    int tile0 = bb * 64;
    int rowA = tile0 + w * 16 + n16;
    bool rvalid = rowA < NN;

    bf16x8 afr[4];
#pragma unroll
    for (int c = 0; c < 4; ++c) {
        float4 xa = make_float4(0.f, 0.f, 0.f, 0.f), xb = xa;
        if (rvalid) {
            const float* px = &x[(size_t)rowA * DIN + c * 32 + quad * 8];
            xa = *(const float4*)px;
            xb = *(const float4*)(px + 4);
        }
        afr[c][0] = (short)f2bf(xa.x); afr[c][1] = (short)f2bf(xa.y);
        afr[c][2] = (short)f2bf(xa.z); afr[c][3] = (short)f2bf(xa.w);
        afr[c][4] = (short)f2bf(xb.x); afr[c][5] = (short)f2bf(xb.y);
        afr[c][6] = (short)f2bf(xb.z); afr[c][7] = (short)f2bf(xb.w);
    }

    f32x4 accP[4] = {{0.f, 0.f, 0.f, 0.f}, {0.f, 0.f, 0.f, 0.f}, {0.f, 0.f, 0.f, 0.f}, {0.f, 0.f, 0.f, 0.f}};
    f32x4 accM[4] = {{0.f, 0.f, 0.f, 0.f}, {0.f, 0.f, 0.f, 0.f}, {0.f, 0.f, 0.f, 0.f}, {0.f, 0.f, 0.f, 0.f}};
#pragma unroll
    for (int c = 0; c < 4; ++c) {
#pragma unroll
        for (int t = 0; t < 4; ++t) {
            bf16x8 bp = *(const bf16x8*)&pWt[(size_t)(t * 16 + n16) * 128 + c * 32 + quad * 8];
            bf16x8 bm = *(const bf16x8*)&W1t[(size_t)(t * 16 + n16) * 128 + c * 32 + quad * 8];
            accP[t] = __builtin_amdgcn_mfma_f32_16x16x32_bf16(afr[c], bp, accP[t], 0, 0, 0);
            accM[t] = __builtin_amdgcn_mfma_f32_16x16x32_bf16(afr[c], bm, accM[t], 0, 0, 0);
        }
    }

    // D layout: col = t*16 + n16, row = w*16 + quad*4 + reg
#pragma unroll
    for (int r = 0; r < 4; ++r) {
        int gn = tile0 + w * 16 + quad * 4 + r;
        if (gn < NN) {
#pragma unroll
            for (int t = 0; t < 4; ++t) {
                int col = t * 16 + n16;
                h0b[(size_t)gn * 64 + col] = f2bf(accP[t][r] + pb[col]);
            }
        }
    }

    float vals1[4][4];
    float mu_[4], rs_[4];
#pragma unroll
    for (int r = 0; r < 4; ++r) {
        float s = 0.f, q = 0.f;
#pragma unroll
        for (int t = 0; t < 4; ++t) {
            float v = accM[t][r] + b1[t * 16 + n16];
            vals1[r][t] = v; s += v; q += v * v;
        }
#pragma unroll
        for (int m = 1; m < 16; m <<= 1) { s += __shfl_xor(s, m); q += __shfl_xor(q, m); }
        float mu = s * (1.f / 64.f);
        float var = q * (1.f / 64.f) - mu * mu;
        mu_[r] = mu; rs_[r] = rsqrtf(var + 1e-5f);
    }
#pragma unroll
    for (int r = 0; r < 4; ++r) {
#pragma unroll
        for (int t = 0; t < 4; ++t) {
            int col = t * 16 + n16;
            float m = (vals1[r][t] - mu_[r]) * rs_[r] * g1[col] + be1[col];
            m1s[w * 1024 + (quad * 4 + r) * 64 + col] = f2bf(fmaxf(m, 0.f));
        }
    }
    __syncthreads();

    bf16x8 a2[2];
#pragma unroll
    for (int c = 0; c < 2; ++c)
        a2[c] = *(const bf16x8*)&m1s[w * 1024 + n16 * 64 + c * 32 + quad * 8];
    f32x4 acc2[4] = {{0.f, 0.f, 0.f, 0.f}, {0.f, 0.f, 0.f, 0.f}, {0.f, 0.f, 0.f, 0.f}, {0.f, 0.f, 0.f, 0.f}};
#pragma unroll
    for (int c = 0; c < 2; ++c) {
#pragma unroll
        for (int t = 0; t < 4; ++t) {
            bf16x8 b4 = *(const bf16x8*)&W2t[(size_t)(t * 16 + n16) * 64 + c * 32 + quad * 8];
            acc2[t] = __builtin_amdgcn_mfma_f32_16x16x32_bf16(a2[c], b4, acc2[t], 0, 0, 0);
        }
    }

#pragma unroll
    for (int r = 0; r < 4; ++r) {
        float s = 0.f, q = 0.f;
        float vr[4];
#pragma unroll
        for (int t = 0; t < 4; ++t) {
            float v = acc2[t][r] + b2[t * 16 + n16];
            vr[t] = v; s += v; q += v * v;
        }
#pragma unroll
        for (int m = 1; m < 16; m <<= 1) { s += __shfl_xor(s, m); q += __shfl_xor(q, m); }
        float mu = s * (1.f / 64.f);
        float var = q * (1.f / 64.f) - mu * mu;
        float rs = rsqrtf(var + 1e-5f);
        float p = 0.f;
#pragma unroll
        for (int t = 0; t < 4; ++t) {
            int col = t * 16 + n16;
            float m = fmaxf((vr[t] - mu) * rs * g2[col] + be2[col], 0.f);
            p += m * w3[col];
        }
#pragma unroll
        for (int m = 1; m < 16; m <<= 1) p += __shfl_xor(p, m);
        if (n16 == 0) {
            int gn = tile0 + w * 16 + quad * 4 + r;
            if (gn < NN) out[gn] = 0.5f * (p + b3[0]);
        }
    }
}

// ---------------- shared gather body (round-0 frozen form) ----------------
__device__ __forceinline__ void gather_row(const int2* __restrict__ ep, int e, int e1,
                                           const unsigned short* __restrict__ hbin, int hl,
                                           float& a0, float& a1, float& a2, float& a3) {
    for (; e + 8 <= e1; e += 8) {
        int2 m[8];
#pragma unroll
        for (int j = 0; j < 8; ++j) m[j] = ep[e + j];
        uint2 p[8];
#pragma unroll
        for (int j = 0; j < 8; ++j)
            p[j] = *(const uint2*)&hbin[(size_t)m[j].x * 64 + hl * 4];
#pragma unroll
        for (int j = 0; j < 8; ++j) {
            float w = __int_as_float(m[j].y);
            a0 += w * bf2f(p[j].x & 0xffffu); a1 += w * bf2f(p[j].x >> 16);
            a2 += w * bf2f(p[j].y & 0xffffu); a3 += w * bf2f(p[j].y >> 16);
        }
    }
    if (e + 4 <= e1) {
        int2 m[4];
#pragma unroll
        for (int j = 0; j < 4; ++j) m[j] = ep[e + j];
        uint2 p[4];
#pragma unroll
        for (int j = 0; j < 4; ++j)
            p[j] = *(const uint2*)&hbin[(size_t)m[j].x * 64 + hl * 4];
#pragma unroll
        for (int j = 0; j < 4; ++j) {
            float w = __int_as_float(m[j].y);
            a0 += w * bf2f(p[j].x & 0xffffu); a1 += w * bf2f(p[j].x >> 16);
            a2 += w * bf2f(p[j].y & 0xffffu); a3 += w * bf2f(p[j].y >> 16);
        }
        e += 4;
    }
    for (; e < e1; ++e) {
        int2 m = ep[e];
        uint2 p = *(const uint2*)&hbin[(size_t)m.x * 64 + hl * 4];
        float w = __int_as_float(m.y);
        a0 += w * bf2f(p.x & 0xffffu); a1 += w * bf2f(p.x >> 16);
        a2 += w * bf2f(p.y & 0xffffu); a3 += w * bf2f(p.y >> 16);
    }
}

// ---------------- layer 1 + folded STABLE (dst, src-phase) sort: ep -> ep2 CSR, rp; then gather ----------------
// Key widened from dstlocal (64 bins) to dstlocal*8 + (src>>14) (512 bins): rows stay contiguous
// (identical rp semantics), but within each row edges are in ascending src-region order. All
// co-resident blocks sweep src phases together -> gather working set ~2 MB instead of 12.8 MB.
__global__ __launch_bounds__(256) void k_layer1(const int2* __restrict__ ep, const int* __restrict__ cnt,
                                                int2* __restrict__ ep2, int* __restrict__ rp,
                                                const unsigned short* __restrict__ h0b,
                                                const float* __restrict__ M,
                                                unsigned short* __restrict__ hbout) {
    __shared__ float As[64 * 65];
    __shared__ int rps[65];
    int* cnt512 = (int*)As;            // alias: sort scratch lives in As before As is written
    int* cur512 = ((int*)As) + 512;    // 4 KB total, As is 16.6 KB
    int tid = threadIdx.x;
    int b = blockIdx.x;
    int tile0 = b * 64;
    size_t base = (size_t)b * STRIDE;
    int cntb = cnt[b];

    // --- stable two-level counting sort ---
    for (int t = tid; t < 512; t += 256) cnt512[t] = 0;
    __syncthreads();
    for (int e = tid; e < cntb; e += 256) {
        int mx = ep[base + e].x;
        atomicAdd(&cnt512[(((mx >> 17) & 63) << 3) | ((mx & 0x1FFFF) >> 14)], 1);
    }
    __syncthreads();
    if (tid == 0) {
        int run = 0;
        for (int r = 0; r < 64; ++r) {
            rps[r] = run;
#pragma unroll
            for (int p = 0; p < 8; ++p) run += cnt512[(r << 3) | p];
        }
        rps[64] = run;
    }
    __syncthreads();
    if (tid < 64) {
        int run = rps[tid];
#pragma unroll
        for (int p = 0; p < 8; ++p) {
            int c = cnt512[(tid << 3) | p];
            cur512[(tid << 3) | p] = run;
            run += c;
        }
    }
    __syncthreads();
    for (int e = tid; e < cntb; e += 256) {
        int2 m = ep[base + e];
        int key = (((m.x >> 17) & 63) << 3) | ((m.x & 0x1FFFF) >> 14);
        int pos = atomicAdd(&cur512[key], 1);
        ep2[base + pos] = make_int2(m.x & 0x1FFFF, m.y);
    }
    __syncthreads();   // ep2 visible to block; rps final; sort scratch dead -> As reusable
    if (tid < 65) rp[b * 65 + tid] = (int)(base + rps[tid]);

    // --- gather (layer 1: hbin = h0b) ---
    int wid = tid >> 6, lane = tid & 63;
    int g = lane >> 4, hl = lane & 15;
#pragma unroll 1
    for (int i = 0; i < 4; ++i) {
        int r = wid * 16 + i * 4 + g;
        int node = tile0 + r;
        float a0 = 0.f, a1 = 0.f, a2 = 0.f, a3 = 0.f;
        if (node < NN) {
            gather_row(ep2, (int)base + rps[r], (int)base + rps[r + 1], h0b, hl, a0, a1, a2, a3);
            uint2 hv = *(const uint2*)&h0b[(size_t)node * 64 + hl * 4];
            a0 += 0.1f * bf2f(hv.x & 0xffffu); a1 += 0.1f * bf2f(hv.x >> 16);
            a2 += 0.1f * bf2f(hv.y & 0xffffu); a3 += 0.1f * bf2f(hv.y >> 16);
        }
        As[r * 65 + hl * 4 + 0] = a0;
        As[r * 65 + hl * 4 + 1] = a1;
        As[r * 65 + hl * 4 + 2] = a2;
        As[r * 65 + hl * 4 + 3] = a3;
    }
    __syncthreads();

    int cc = tid & 15, nc = tid >> 4;
    float acc[4][4] = {{0.f}};
#pragma unroll 8
    for (int k = 0; k < 64; ++k) {
        float4 b4 = *(const float4*)&M[k * 64 + cc * 4];
        float a0x = As[(nc * 4 + 0) * 65 + k];
        float a1x = As[(nc * 4 + 1) * 65 + k];
        float a2x = As[(nc * 4 + 2) * 65 + k];
        float a3x = As[(nc * 4 + 3) * 65 + k];
        acc[0][0] += a0x * b4.x; acc[0][1] += a0x * b4.y; acc[0][2] += a0x * b4.z; acc[0][3] += a0x * b4.w;
        acc[1][0] += a1x * b4.x; acc[1][1] += a1x * b4.y; acc[1][2] += a1x * b4.z; acc[1][3] += a1x * b4.w;
        acc[2][0] += a2x * b4.x; acc[2][1] += a2x * b4.y; acc[2][2] += a2x * b4.z; acc[2][3] += a2x * b4.w;
        acc[3][0] += a3x * b4.x; acc[3][1] += a3x * b4.y; acc[3][2] += a3x * b4.z; acc[3][3] += a3x * b4.w;
    }
#pragma unroll
    for (int i = 0; i < 4; ++i) {
        int gn = tile0 + nc * 4 + i;
        if (gn >= NN) continue;
        ushort4 ob;
        ob.x = f2bf(fmaxf(acc[i][0], 0.f));
        ob.y = f2bf(fmaxf(acc[i][1], 0.f));
        ob.z = f2bf(fmaxf(acc[i][2], 0.f));
        ob.w = f2bf(fmaxf(acc[i][3], 0.f));
        *(ushort4*)&hbout[(size_t)gn * 64 + cc * 4] = ob;
    }
}

// ---------------- layers 2..3: standard gather, row bounds from rp ----------------
__global__ __launch_bounds__(256) void k_layer(const int2* __restrict__ ep2, const int* __restrict__ rp,
                                               const unsigned short* __restrict__ hbin,
                                               const unsigned short* __restrict__ h0b,
                                               const float* __restrict__ M,
                                               unsigned short* __restrict__ hbout) {
    __shared__ float As[64 * 65];
    int tid = threadIdx.x;
    int wid = tid >> 6, lane = tid & 63;
    int g = lane >> 4, hl = lane & 15;
    int tile0 = blockIdx.x * 64;

#pragma unroll 1
    for (int i = 0; i < 4; ++i) {
        int r = wid * 16 + i * 4 + g;
        int node = tile0 + r;
        float a0 = 0.f, a1 = 0.f, a2 = 0.f, a3 = 0.f;
        if (node < NN) {
            int e0 = rp[blockIdx.x * 65 + r], e1 = rp[blockIdx.x * 65 + r + 1];
            gather_row(ep2, e0, e1, hbin, hl, a0, a1, a2, a3);
            uint2 hv = *(const uint2*)&h0b[(size_t)node * 64 + hl * 4];
            a0 += 0.1f * bf2f(hv.x & 0xffffu); a1 += 0.1f * bf2f(hv.x >> 16);
            a2 += 0.1f * bf2f(hv.y & 0xffffu); a3 += 0.1f * bf2f(hv.y >> 16);
        }
        As[r * 65 + hl * 4 + 0] = a0;
        As[r * 65 + hl * 4 + 1] = a1;
        As[r * 65 + hl * 4 + 2] = a2;
        As[r * 65 + hl * 4 + 3] = a3;
    }
    __syncthreads();

    int cc = tid & 15, nc = tid >> 4;
    float acc[4][4] = {{0.f}};
#pragma unroll 8
    for (int k = 0; k < 64; ++k) {
        float4 b4 = *(const float4*)&M[k * 64 + cc * 4];
        float a0x = As[(nc * 4 + 0) * 65 + k];
        float a1x = As[(nc * 4 + 1) * 65 + k];
        float a2x = As[(nc * 4 + 2) * 65 + k];
        float a3x = As[(nc * 4 + 3) * 65 + k];
        acc[0][0] += a0x * b4.x; acc[0][1] += a0x * b4.y; acc[0][2] += a0x * b4.z; acc[0][3] += a0x * b4.w;
        acc[1][0] += a1x * b4.x; acc[1][1] += a1x * b4.y; acc[1][2] += a1x * b4.z; acc[1][3] += a1x * b4.w;
        acc[2][0] += a2x * b4.x; acc[2][1] += a2x * b4.y; acc[2][2] += a2x * b4.z; acc[2][3] += a2x * b4.w;
        acc[3][0] += a3x * b4.x; acc[3][1] += a3x * b4.y; acc[3][2] += a3x * b4.z; acc[3][3] += a3x * b4.w;
    }
#pragma unroll
    for (int i = 0; i < 4; ++i) {
        int gn = tile0 + nc * 4 + i;
        if (gn >= NN) continue;
        ushort4 ob;
        ob.x = f2bf(fmaxf(acc[i][0], 0.f));
        ob.y = f2bf(fmaxf(acc[i][1], 0.f));
        ob.z = f2bf(fmaxf(acc[i][2], 0.f));
        ob.w = f2bf(fmaxf(acc[i][3], 0.f));
        *(ushort4*)&hbout[(size_t)gn * 64 + cc * 4] = ob;
    }
}

// ---------------- layer 4 + folded JK-max/head: out += 0.5*(max(h1..h4) @ hw + hb) ----------------
__global__ __launch_bounds__(256) void k_layer4(const int2* __restrict__ ep2, const int* __restrict__ rp,
                                                const unsigned short* __restrict__ hbin,   // h3
                                                const unsigned short* __restrict__ h0b,
                                                const float* __restrict__ M,
                                                const unsigned short* __restrict__ h1,
                                                const unsigned short* __restrict__ h2,
                                                const unsigned short* __restrict__ h3,
                                                const float* __restrict__ hw,
                                                const float* __restrict__ hbias,
                                                float* __restrict__ out) {
    __shared__ float As[64 * 65];
    int tid = threadIdx.x;
    int wid = tid >> 6, lane = tid & 63;
    int g = lane >> 4, hl = lane & 15;
    int tile0 = blockIdx.x * 64;

#pragma unroll 1
    for (int i = 0; i < 4; ++i) {
        int r = wid * 16 + i * 4 + g;
        int node = tile0 + r;
        float a0 = 0.f, a1 = 0.f, a2 = 0.f, a3 = 0.f;
        if (node < NN) {
            int e0 = rp[blockIdx.x * 65 + r], e1 = rp[blockIdx.x * 65 + r + 1];
            gather_row(ep2, e0, e1, hbin, hl, a0, a1, a2, a3);
            uint2 hv = *(const uint2*)&h0b[(size_t)node * 64 + hl * 4];
            a0 += 0.1f * bf2f(hv.x & 0xffffu); a1 += 0.1f * bf2f(hv.x >> 16);
            a2 += 0.1f * bf2f(hv.y & 0xffffu); a3 += 0.1f * bf2f(hv.y >> 16);
        }
        As[r * 65 + hl * 4 + 0] = a0;
        As[r * 65 + hl * 4 + 1] = a1;
        As[r * 65 + hl * 4 + 2] = a2;
        As[r * 65 + hl * 4 + 3] = a3;
    }
    __syncthreads();

    int cc = tid & 15, nc = tid >> 4;
    float acc[4][4] = {{0.f}};
#pragma unroll 8
    for (int k = 0; k < 64; ++k) {
        float4 b4 = *(const float4*)&M[k * 64 + cc * 4];
        float a0x = As[(nc * 4 + 0) * 65 + k];
        float a1x = As[(nc * 4 + 1) * 65 + k];
        float a2x = As[(nc * 4 + 2) * 65 + k];
        float a3x = As[(nc * 4 + 3) * 65 + k];
        acc[0][0] += a0x * b4.x; acc[0][1] += a0x * b4.y; acc[0][2] += a0x * b4.z; acc[0][3] += a0x * b4.w;
        acc[1][0] += a1x * b4.x; acc[1][1] += a1x * b4.y; acc[1][2] += a1x * b4.z; acc[1][3] += a1x * b4.w;
        acc[2][0] += a2x * b4.x; acc[2][1] += a2x * b4.y; acc[2][2] += a2x * b4.z; acc[2][3] += a2x * b4.w;
        acc[3][0] += a3x * b4.x; acc[3][1] += a3x * b4.y; acc[3][2] += a3x * b4.z; acc[3][3] += a3x * b4.w;
    }
    float hw4[4];
#pragma unroll
    for (int j = 0; j < 4; ++j) hw4[j] = hw[cc * 4 + j];
#pragma unroll
    for (int i = 0; i < 4; ++i) {
        int gn = tile0 + nc * 4 + i;
        float p = 0.f;
        if (gn < NN) {
            size_t q = (size_t)gn * 64 + cc * 4;
            uint2 v1 = *(const uint2*)&h1[q];
            uint2 v2 = *(const uint2*)&h2[q];
            uint2 v3 = *(const uint2*)&h3[q];
            float m0 = fmaxf(acc[i][0], 0.f);
            float m1 = fmaxf(acc[i][1], 0.f);
            float m2 = fmaxf(acc[i][2], 0.f);
            float m3 = fmaxf(acc[i][3], 0.f);
            m0 = fmaxf(m0, fmaxf(bf2f(v1.x & 0xffffu), fmaxf(bf2f(v2.x & 0xffffu), bf2f(v3.x & 0xffffu))));
            m1 = fmaxf(m1, fmaxf(bf2f(v1.x >> 16), fmaxf(bf2f(v2.x >> 16), bf2f(v3.x >> 16))));
            m2 = fmaxf(m2, fmaxf(bf2f(v1.y & 0xffffu), fmaxf(bf2f(v2.y & 0xffffu), bf2f(v3.y & 0xffffu))));
            m3 = fmaxf(m3, fmaxf(bf2f(v1.y >> 16), fmaxf(bf2f(v2.y >> 16), bf2f(v3.y >> 16))));
            p = m0 * hw4[0] + m1 * hw4[1] + m2 * hw4[2] + m3 * hw4[3];
        }
#pragma unroll
        for (int m = 1; m < 16; m <<= 1) p += __shfl_xor(p, m);
        if (cc == 0 && gn < NN) out[gn] = out[gn] + 0.5f * (p + hbias[0]);
    }
}

extern "C" void kernel_launch(void* const* d_in, const int* in_sizes, int n_in,
                              void* d_out, int out_size, void* d_ws, size_t ws_size,
                              hipStream_t stream) {
    const float* x      = (const float*)d_in[0];
    const float* ew     = (const float*)d_in[1];
    const float* proj_w = (const float*)d_in[2];
    const float* proj_b = (const float*)d_in[3];
    const float* gcn_w  = (const float*)d_in[4];
    const float* w1     = (const float*)d_in[5];
    const float* b1     = (const float*)d_in[6];
    const float* g1     = (const float*)d_in[7];
    const float* be1    = (const float*)d_in[8];
    const float* w2     = (const float*)d_in[9];
    const float* b2     = (const float*)d_in[10];
    const float* g2     = (const float*)d_in[11];
    const float* be2    = (const float*)d_in[12];
    const float* w3     = (const float*)d_in[13];
    const float* b3     = (const float*)d_in[14];
    const float* hw     = (const float*)d_in[15];
    const float* hb     = (const float*)d_in[16];
    const int*   ei     = (const int*)d_in[17];
    float* out = (float*)d_out;

    char* ws = (char*)d_ws;
    size_t off = 0;
    auto alloc = [&](size_t bytes) { size_t o = off; off += (bytes + 255) & ~(size_t)255; return o; };
    unsigned short* h0b = (unsigned short*)(ws + alloc((size_t)NN * 64 * 2));
    unsigned short* hl1 = (unsigned short*)(ws + alloc((size_t)NN * 64 * 2));
    unsigned short* hl2 = (unsigned short*)(ws + alloc((size_t)NN * 64 * 2));
    unsigned short* hl3 = (unsigned short*)(ws + alloc((size_t)NN * 64 * 2));
    float* M       = (float*)(ws + alloc((size_t)4 * 64 * 64 * 4));
    unsigned short* pWt = (unsigned short*)(ws + alloc((size_t)8192 * 2));
    unsigned short* W1t = (unsigned short*)(ws + alloc((size_t)8192 * 2));
    unsigned short* W2t = (unsigned short*)(ws + alloc((size_t)4096 * 2));
    int*   cnt     = (int*)(ws + alloc((size_t)NBUK * 4));
    int*   rp      = (int*)(ws + alloc((size_t)NBUK * 65 * 4));
    int2*  ep      = (int2*)(ws + alloc((size_t)NBUK * STRIDE * 8));
    int2*  ep2     = (int2*)(ws + alloc((size_t)NBUK * STRIDE * 8));

    const int* srcv = ei;
    const int* dstv = ei + NE;

    hipMemsetAsync(cnt, 0, (size_t)NBUK * 4, stream);

    k_wprep<<<80, 256, 0, stream>>>(proj_w, w1, w2, pWt, W1t, W2t);

    // front: MFMA projmlp || bscatter || mprep  (theta_l = log(1/(l+1) + 1))
    k_front<<<NBUK + NBLK + 64, 256, 0, stream>>>(x, pWt, proj_b, W1t, b1, g1, be1,
        W2t, b2, g2, be2, w3, b3, h0b, out, srcv, dstv, ew, cnt, ep, gcn_w, M,
        make_float4(0.69314718055994531f, 0.40546510810816438f,
                    0.28768207245178085f, 0.22314355131420976f));

    k_layer1<<<NBUK, 256, 0, stream>>>(ep, cnt, ep2, rp, h0b, M + 0 * 4096, hl1);
    k_layer<<<NBUK, 256, 0, stream>>>(ep2, rp, hl1, h0b, M + 1 * 4096, hl2);
    k_layer<<<NBUK, 256, 0, stream>>>(ep2, rp, hl2, h0b, M + 2 * 4096, hl3);
    k_layer4<<<NBUK, 256, 0, stream>>>(ep2, rp, hl3, h0b, M + 3 * 4096,
                                       hl1, hl2, hl3, hw, hb, out);
}

// Round 7
// 399.007 us; speedup vs baseline: 6.5644x; 1.0470x over previous
//
#include <hip/hip_runtime.h>

#define NN 100000
#define NE 1600000
#define DIN 128
#define HD 64
#define NBUK 1563          // ceil(100000/64) buckets of 64 nodes
#define EPB 2560           // edges per block in bucket build
#define NBLK 625           // 625 * 2560 = 1,600,000
#define STRIDE 1536        // fixed bucket capacity (mean 1024, sigma 32 -> 16 sigma margin)

typedef __attribute__((ext_vector_type(8))) short bf16x8;
typedef __attribute__((ext_vector_type(4))) float f32x4;

__device__ __forceinline__ unsigned short f2bf(float f) {
    unsigned int u = __float_as_uint(f);
    u += 0x7fff + ((u >> 16) & 1);     // round-to-nearest-even
    return (unsigned short)(u >> 16);
}
__device__ __forceinline__ float bf2f(unsigned int lo16) {
    return __uint_as_float(lo16 << 16);
}

// ---------------- weight prep: bf16 transposed tables Wt[n][k]; also zeros cnt (folds memset) ----------------
__global__ __launch_bounds__(256) void k_wprep(const float* __restrict__ pW, const float* __restrict__ W1,
                                               const float* __restrict__ W2,
                                               unsigned short* __restrict__ pWt,
                                               unsigned short* __restrict__ W1t,
                                               unsigned short* __restrict__ W2t,
                                               int* __restrict__ cnt) {
    int idx = blockIdx.x * 256 + threadIdx.x;   // 80*256 = 20480
    if (idx < NBUK) cnt[idx] = 0;
    if (idx < 8192) {
        int n = idx >> 7, k = idx & 127;
        pWt[idx] = f2bf(pW[k * 64 + n]);
    } else if (idx < 16384) {
        int j = idx - 8192;
        int n = j >> 7, k = j & 127;
        W1t[j] = f2bf(W1[k * 64 + n]);
    } else {
        int j = idx - 16384;
        int n = j >> 6, k = j & 63;
        W2t[j] = f2bf(W2[k * 64 + n]);
    }
}

// ---------------- front: MFMA projmlp (0..NBUK-1) || bscatter (next NBLK) || mprep (last 64) ----------------
// Round-0 frozen form (measured 95.8-100 us). Do not touch.
__global__ __launch_bounds__(256) void k_front(const float* __restrict__ x,
        const unsigned short* __restrict__ pWt, const float* __restrict__ pb,
        const unsigned short* __restrict__ W1t, const float* __restrict__ b1,
        const float* __restrict__ g1, const float* __restrict__ be1,
        const unsigned short* __restrict__ W2t, const float* __restrict__ b2,
        const float* __restrict__ g2, const float* __restrict__ be2,
        const float* __restrict__ w3, const float* __restrict__ b3,
        unsigned short* __restrict__ h0b, float* __restrict__ out,
        const int* __restrict__ src, const int* __restrict__ dst, const float* __restrict__ ew,
        int* __restrict__ cnt, int2* __restrict__ ep,
        const float* __restrict__ gw, float* __restrict__ M, float4 th) {
    __shared__ int shmem[2 * NBUK];               // 12504 B; projmlp aliases first 8 KB as bf16 m1s
    unsigned short* m1s = (unsigned short*)shmem;
    int tid = threadIdx.x;
    int bb = blockIdx.x;

    if (bb >= NBUK) {
        if (bb < NBUK + NBLK) {
            // ---- bscatter ----
            int* lh = shmem;
            int* gb = shmem + NBUK;
            for (int b = tid; b < NBUK; b += 256) lh[b] = 0;
            __syncthreads();
            int base = (bb - NBUK) * EPB + tid;
#pragma unroll
            for (int i = 0; i < EPB / 256; ++i)
                atomicAdd(&lh[dst[base + i * 256] >> 6], 1);
            __syncthreads();
            for (int b = tid; b < NBUK; b += 256) {
                int c = lh[b];
                if (c) gb[b] = atomicAdd(&cnt[b], c);
            }
            __syncthreads();
#pragma unroll
            for (int i = 0; i < EPB / 256; ++i) {
                int e = base + i * 256;
                int d = dst[e];
                int b = d >> 6;
                int pos = atomicAdd(&gb[b], 1);
                ep[(size_t)b * STRIDE + pos] = make_int2(src[e] | ((d & 63) << 17),
                                                         __float_as_int(0.9f * ew[e]));
            }
        } else {
            // ---- mprep ----
            int idx = (bb - NBUK - NBLK) * 256 + tid;   // < 4*64*64
            int l = idx >> 12;
            int k = (idx >> 6) & 63;
            int c = idx & 63;
            float theta = (l == 0) ? th.x : (l == 1) ? th.y : (l == 2) ? th.z : th.w;
            float m = theta * gw[idx];
            if (k == c) m += (1.f - theta);
            M[idx] = m;
        }
        return;
    }

    // ---- projmlp (MFMA) ----
    int w = tid >> 6, lane = tid & 63;
    int n16 = lane & 15, quad = lane >> 4;
    int tile0 = bb * 64;
    int rowA = tile0 + w * 16 + n16;
    bool rvalid = rowA < NN;

    bf16x8 afr[4];
#pragma unroll
    for (int c = 0; c < 4; ++c) {
        float4 xa = make_float4(0.f, 0.f, 0.f, 0.f), xb = xa;
        if (rvalid) {
            const float* px = &x[(size_t)rowA * DIN + c * 32 + quad * 8];
            xa = *(const float4*)px;
            xb = *(const float4*)(px + 4);
        }
        afr[c][0] = (short)f2bf(xa.x); afr[c][1] = (short)f2bf(xa.y);
        afr[c][2] = (short)f2bf(xa.z); afr[c][3] = (short)f2bf(xa.w);
        afr[c][4] = (short)f2bf(xb.x); afr[c][5] = (short)f2bf(xb.y);
        afr[c][6] = (short)f2bf(xb.z); afr[c][7] = (short)f2bf(xb.w);
    }

    f32x4 accP[4] = {{0.f, 0.f, 0.f, 0.f}, {0.f, 0.f, 0.f, 0.f}, {0.f, 0.f, 0.f, 0.f}, {0.f, 0.f, 0.f, 0.f}};
    f32x4 accM[4] = {{0.f, 0.f, 0.f, 0.f}, {0.f, 0.f, 0.f, 0.f}, {0.f, 0.f, 0.f, 0.f}, {0.f, 0.f, 0.f, 0.f}};
#pragma unroll
    for (int c = 0; c < 4; ++c) {
#pragma unroll
        for (int t = 0; t < 4; ++t) {
            bf16x8 bp = *(const bf16x8*)&pWt[(size_t)(t * 16 + n16) * 128 + c * 32 + quad * 8];
            bf16x8 bm = *(const bf16x8*)&W1t[(size_t)(t * 16 + n16) * 128 + c * 32 + quad * 8];
            accP[t] = __builtin_amdgcn_mfma_f32_16x16x32_bf16(afr[c], bp, accP[t], 0, 0, 0);
            accM[t] = __builtin_amdgcn_mfma_f32_16x16x32_bf16(afr[c], bm, accM[t], 0, 0, 0);
        }
    }

    // D layout: col = t*16 + n16, row = w*16 + quad*4 + reg
#pragma unroll
    for (int r = 0; r < 4; ++r) {
        int gn = tile0 + w * 16 + quad * 4 + r;
        if (gn < NN) {
#pragma unroll
            for (int t = 0; t < 4; ++t) {
                int col = t * 16 + n16;
                h0b[(size_t)gn * 64 + col] = f2bf(accP[t][r] + pb[col]);
            }
        }
    }

    float vals1[4][4];
    float mu_[4], rs_[4];
#pragma unroll
    for (int r = 0; r < 4; ++r) {
        float s = 0.f, q = 0.f;
#pragma unroll
        for (int t = 0; t < 4; ++t) {
            float v = accM[t][r] + b1[t * 16 + n16];
            vals1[r][t] = v; s += v; q += v * v;
        }
#pragma unroll
        for (int m = 1; m < 16; m <<= 1) { s += __shfl_xor(s, m); q += __shfl_xor(q, m); }
        float mu = s * (1.f / 64.f);
        float var = q * (1.f / 64.f) - mu * mu;
        mu_[r] = mu; rs_[r] = rsqrtf(var + 1e-5f);
    }
#pragma unroll
    for (int r = 0; r < 4; ++r) {
#pragma unroll
        for (int t = 0; t < 4; ++t) {
            int col = t * 16 + n16;
            float m = (vals1[r][t] - mu_[r]) * rs_[r] * g1[col] + be1[col];
            m1s[w * 1024 + (quad * 4 + r) * 64 + col] = f2bf(fmaxf(m, 0.f));
        }
    }
    __syncthreads();

    bf16x8 a2[2];
#pragma unroll
    for (int c = 0; c < 2; ++c)
        a2[c] = *(const bf16x8*)&m1s[w * 1024 + n16 * 64 + c * 32 + quad * 8];
    f32x4 acc2[4] = {{0.f, 0.f, 0.f, 0.f}, {0.f, 0.f, 0.f, 0.f}, {0.f, 0.f, 0.f, 0.f}, {0.f, 0.f, 0.f, 0.f}};
#pragma unroll
    for (int c = 0; c < 2; ++c) {
#pragma unroll
        for (int t = 0; t < 4; ++t) {
            bf16x8 b4 = *(const bf16x8*)&W2t[(size_t)(t * 16 + n16) * 64 + c * 32 + quad * 8];
            acc2[t] = __builtin_amdgcn_mfma_f32_16x16x32_bf16(a2[c], b4, acc2[t], 0, 0, 0);
        }
    }

#pragma unroll
    for (int r = 0; r < 4; ++r) {
        float s = 0.f, q = 0.f;
        float vr[4];
#pragma unroll
        for (int t = 0; t < 4; ++t) {
            float v = acc2[t][r] + b2[t * 16 + n16];
            vr[t] = v; s += v; q += v * v;
        }
#pragma unroll
        for (int m = 1; m < 16; m <<= 1) { s += __shfl_xor(s, m); q += __shfl_xor(q, m); }
        float mu = s * (1.f / 64.f);
        float var = q * (1.f / 64.f) - mu * mu;
        float rs = rsqrtf(var + 1e-5f);
        float p = 0.f;
#pragma unroll
        for (int t = 0; t < 4; ++t) {
            int col = t * 16 + n16;
            float m = fmaxf((vr[t] - mu) * rs * g2[col] + be2[col], 0.f);
            p += m * w3[col];
        }
#pragma unroll
        for (int m = 1; m < 16; m <<= 1) p += __shfl_xor(p, m);
        if (n16 == 0) {
            int gn = tile0 + w * 16 + quad * 4 + r;
            if (gn < NN) out[gn] = 0.5f * (p + b3[0]);
        }
    }
}

// ---------------- cooperative gather: quarter-wave fetches a 16-edge window in ONE coalesced load,
// redistributes via shfl (VALU, off the VMEM chain), then issues the random h-loads.
// Exposed latency per 16-edge row: L_ep2 + 2*L_p  (was 2*L_ep2 + 2*L_p with 16x more ep2 instrs).
__device__ __forceinline__ void gather_row16(const int2* __restrict__ ep, int e0, int e1,
                                             const unsigned short* __restrict__ hbin,
                                             int qb, int hl,
                                             float& a0, float& a1, float& a2, float& a3) {
    for (int w0 = e0; w0 < e1; w0 += 16) {
        int nb = e1 - w0; if (nb > 16) nb = 16;
        int2 mine = ep[w0 + hl];               // 16 lanes fetch 16 edges (slack-guarded overread)
        int n1 = nb < 8 ? nb : 8;
        int n2 = nb - n1;
        int mxs[8];
#pragma unroll
        for (int j = 0; j < 8; ++j) mxs[j] = __shfl(mine.x, qb + j);
        uint2 p[8];
#pragma unroll
        for (int j = 0; j < 8; ++j)
            if (j < n1) p[j] = *(const uint2*)&hbin[(size_t)mxs[j] * 64 + hl * 4];
#pragma unroll
        for (int j = 0; j < 8; ++j)
            if (j < n1) {
                float w = __int_as_float(__shfl(mine.y, qb + j));
                a0 += w * bf2f(p[j].x & 0xffffu); a1 += w * bf2f(p[j].x >> 16);
                a2 += w * bf2f(p[j].y & 0xffffu); a3 += w * bf2f(p[j].y >> 16);
            }
#pragma unroll
        for (int j = 0; j < 8; ++j) mxs[j] = __shfl(mine.x, qb + 8 + j);
#pragma unroll
        for (int j = 0; j < 8; ++j)
            if (j < n2) p[j] = *(const uint2*)&hbin[(size_t)mxs[j] * 64 + hl * 4];
#pragma unroll
        for (int j = 0; j < 8; ++j)
            if (j < n2) {
                float w = __int_as_float(__shfl(mine.y, qb + 8 + j));
                a0 += w * bf2f(p[j].x & 0xffffu); a1 += w * bf2f(p[j].x >> 16);
                a2 += w * bf2f(p[j].y & 0xffffu); a3 += w * bf2f(p[j].y >> 16);
            }
    }
}

// ---------------- layer 1 + folded bucket sort (round-0 64-bin form): ep -> ep2 CSR, rp; then gather ----------------
__global__ __launch_bounds__(256) void k_layer1(const int2* __restrict__ ep, const int* __restrict__ cnt,
                                                int2* __restrict__ ep2, int* __restrict__ rp,
                                                const unsigned short* __restrict__ h0b,
                                                const float* __restrict__ M,
                                                unsigned short* __restrict__ hbout) {
    __shared__ float As[64 * 65];
    __shared__ int cnt64[64];
    __shared__ int cur64[64];
    __shared__ int rps[65];
    int tid = threadIdx.x;
    int b = blockIdx.x;
    int tile0 = b * 64;
    size_t base = (size_t)b * STRIDE;
    int cntb = cnt[b];

    // --- sort bucket into CSR row order ---
    if (tid < 64) cnt64[tid] = 0;
    __syncthreads();
    for (int e = tid; e < cntb; e += 256)
        atomicAdd(&cnt64[(ep[base + e].x >> 17) & 63], 1);
    __syncthreads();
    if (tid == 0) {
        int run = 0;
        for (int r = 0; r < 64; ++r) {
            cur64[r] = run;
            rps[r] = run;
            run += cnt64[r];
        }
        rps[64] = run;
    }
    __syncthreads();
    for (int e = tid; e < cntb; e += 256) {
        int2 m = ep[base + e];
        int r = (m.x >> 17) & 63;
        int pos = atomicAdd(&cur64[r], 1);
        ep2[base + pos] = make_int2(m.x & 0x1FFFF, m.y);
    }
    __syncthreads();   // ep2 visible to block; rps final
    if (tid < 65) rp[b * 65 + tid] = (int)(base + rps[tid]);

    // --- gather (layer 1: hbin = h0b) ---
    int wid = tid >> 6, lane = tid & 63;
    int g = lane >> 4, hl = lane & 15, qb = lane & 48;
#pragma unroll 1
    for (int i = 0; i < 4; ++i) {
        int r = wid * 16 + i * 4 + g;
        int node = tile0 + r;
        float a0 = 0.f, a1 = 0.f, a2 = 0.f, a3 = 0.f;
        if (node < NN) {
            gather_row16(ep2, (int)base + rps[r], (int)base + rps[r + 1], h0b, qb, hl, a0, a1, a2, a3);
            uint2 hv = *(const uint2*)&h0b[(size_t)node * 64 + hl * 4];
            a0 += 0.1f * bf2f(hv.x & 0xffffu); a1 += 0.1f * bf2f(hv.x >> 16);
            a2 += 0.1f * bf2f(hv.y & 0xffffu); a3 += 0.1f * bf2f(hv.y >> 16);
        }
        As[r * 65 + hl * 4 + 0] = a0;
        As[r * 65 + hl * 4 + 1] = a1;
        As[r * 65 + hl * 4 + 2] = a2;
        As[r * 65 + hl * 4 + 3] = a3;
    }
    __syncthreads();

    int cc = tid & 15, nc = tid >> 4;
    float acc[4][4] = {{0.f}};
#pragma unroll 8
    for (int k = 0; k < 64; ++k) {
        float4 b4 = *(const float4*)&M[k * 64 + cc * 4];
        float a0x = As[(nc * 4 + 0) * 65 + k];
        float a1x = As[(nc * 4 + 1) * 65 + k];
        float a2x = As[(nc * 4 + 2) * 65 + k];
        float a3x = As[(nc * 4 + 3) * 65 + k];
        acc[0][0] += a0x * b4.x; acc[0][1] += a0x * b4.y; acc[0][2] += a0x * b4.z; acc[0][3] += a0x * b4.w;
        acc[1][0] += a1x * b4.x; acc[1][1] += a1x * b4.y; acc[1][2] += a1x * b4.z; acc[1][3] += a1x * b4.w;
        acc[2][0] += a2x * b4.x; acc[2][1] += a2x * b4.y; acc[2][2] += a2x * b4.z; acc[2][3] += a2x * b4.w;
        acc[3][0] += a3x * b4.x; acc[3][1] += a3x * b4.y; acc[3][2] += a3x * b4.z; acc[3][3] += a3x * b4.w;
    }
#pragma unroll
    for (int i = 0; i < 4; ++i) {
        int gn = tile0 + nc * 4 + i;
        if (gn >= NN) continue;
        ushort4 ob;
        ob.x = f2bf(fmaxf(acc[i][0], 0.f));
        ob.y = f2bf(fmaxf(acc[i][1], 0.f));
        ob.z = f2bf(fmaxf(acc[i][2], 0.f));
        ob.w = f2bf(fmaxf(acc[i][3], 0.f));
        *(ushort4*)&hbout[(size_t)gn * 64 + cc * 4] = ob;
    }
}

// ---------------- layers 2..3: standard gather, row bounds from rp ----------------
__global__ __launch_bounds__(256) void k_layer(const int2* __restrict__ ep2, const int* __restrict__ rp,
                                               const unsigned short* __restrict__ hbin,
                                               const unsigned short* __restrict__ h0b,
                                               const float* __restrict__ M,
                                               unsigned short* __restrict__ hbout) {
    __shared__ float As[64 * 65];
    int tid = threadIdx.x;
    int wid = tid >> 6, lane = tid & 63;
    int g = lane >> 4, hl = lane & 15, qb = lane & 48;
    int tile0 = blockIdx.x * 64;

#pragma unroll 1
    for (int i = 0; i < 4; ++i) {
        int r = wid * 16 + i * 4 + g;
        int node = tile0 + r;
        float a0 = 0.f, a1 = 0.f, a2 = 0.f, a3 = 0.f;
        if (node < NN) {
            int e0 = rp[blockIdx.x * 65 + r], e1 = rp[blockIdx.x * 65 + r + 1];
            gather_row16(ep2, e0, e1, hbin, qb, hl, a0, a1, a2, a3);
            uint2 hv = *(const uint2*)&h0b[(size_t)node * 64 + hl * 4];
            a0 += 0.1f * bf2f(hv.x & 0xffffu); a1 += 0.1f * bf2f(hv.x >> 16);
            a2 += 0.1f * bf2f(hv.y & 0xffffu); a3 += 0.1f * bf2f(hv.y >> 16);
        }
        As[r * 65 + hl * 4 + 0] = a0;
        As[r * 65 + hl * 4 + 1] = a1;
        As[r * 65 + hl * 4 + 2] = a2;
        As[r * 65 + hl * 4 + 3] = a3;
    }
    __syncthreads();

    int cc = tid & 15, nc = tid >> 4;
    float acc[4][4] = {{0.f}};
#pragma unroll 8
    for (int k = 0; k < 64; ++k) {
        float4 b4 = *(const float4*)&M[k * 64 + cc * 4];
        float a0x = As[(nc * 4 + 0) * 65 + k];
        float a1x = As[(nc * 4 + 1) * 65 + k];
        float a2x = As[(nc * 4 + 2) * 65 + k];
        float a3x = As[(nc * 4 + 3) * 65 + k];
        acc[0][0] += a0x * b4.x; acc[0][1] += a0x * b4.y; acc[0][2] += a0x * b4.z; acc[0][3] += a0x * b4.w;
        acc[1][0] += a1x * b4.x; acc[1][1] += a1x * b4.y; acc[1][2] += a1x * b4.z; acc[1][3] += a1x * b4.w;
        acc[2][0] += a2x * b4.x; acc[2][1] += a2x * b4.y; acc[2][2] += a2x * b4.z; acc[2][3] += a2x * b4.w;
        acc[3][0] += a3x * b4.x; acc[3][1] += a3x * b4.y; acc[3][2] += a3x * b4.z; acc[3][3] += a3x * b4.w;
    }
#pragma unroll
    for (int i = 0; i < 4; ++i) {
        int gn = tile0 + nc * 4 + i;
        if (gn >= NN) continue;
        ushort4 ob;
        ob.x = f2bf(fmaxf(acc[i][0], 0.f));
        ob.y = f2bf(fmaxf(acc[i][1], 0.f));
        ob.z = f2bf(fmaxf(acc[i][2], 0.f));
        ob.w = f2bf(fmaxf(acc[i][3], 0.f));
        *(ushort4*)&hbout[(size_t)gn * 64 + cc * 4] = ob;
    }
}

// ---------------- layer 4 + folded JK-max/head: out += 0.5*(max(h1..h4) @ hw + hb) ----------------
__global__ __launch_bounds__(256) void k_layer4(const int2* __restrict__ ep2, const int* __restrict__ rp,
                                                const unsigned short* __restrict__ hbin,   // h3
                                                const unsigned short* __restrict__ h0b,
                                                const float* __restrict__ M,
                                                const unsigned short* __restrict__ h1,
                                                const unsigned short* __restrict__ h2,
                                                const unsigned short* __restrict__ h3,
                                                const float* __restrict__ hw,
                                                const float* __restrict__ hbias,
                                                float* __restrict__ out) {
    __shared__ float As[64 * 65];
    int tid = threadIdx.x;
    int wid = tid >> 6, lane = tid & 63;
    int g = lane >> 4, hl = lane & 15, qb = lane & 48;
    int tile0 = blockIdx.x * 64;

#pragma unroll 1
    for (int i = 0; i < 4; ++i) {
        int r = wid * 16 + i * 4 + g;
        int node = tile0 + r;
        float a0 = 0.f, a1 = 0.f, a2 = 0.f, a3 = 0.f;
        if (node < NN) {
            int e0 = rp[blockIdx.x * 65 + r], e1 = rp[blockIdx.x * 65 + r + 1];
            gather_row16(ep2, e0, e1, hbin, qb, hl, a0, a1, a2, a3);
            uint2 hv = *(const uint2*)&h0b[(size_t)node * 64 + hl * 4];
            a0 += 0.1f * bf2f(hv.x & 0xffffu); a1 += 0.1f * bf2f(hv.x >> 16);
            a2 += 0.1f * bf2f(hv.y & 0xffffu); a3 += 0.1f * bf2f(hv.y >> 16);
        }
        As[r * 65 + hl * 4 + 0] = a0;
        As[r * 65 + hl * 4 + 1] = a1;
        As[r * 65 + hl * 4 + 2] = a2;
        As[r * 65 + hl * 4 + 3] = a3;
    }
    __syncthreads();

    int cc = tid & 15, nc = tid >> 4;
    float acc[4][4] = {{0.f}};
#pragma unroll 8
    for (int k = 0; k < 64; ++k) {
        float4 b4 = *(const float4*)&M[k * 64 + cc * 4];
        float a0x = As[(nc * 4 + 0) * 65 + k];
        float a1x = As[(nc * 4 + 1) * 65 + k];
        float a2x = As[(nc * 4 + 2) * 65 + k];
        float a3x = As[(nc * 4 + 3) * 65 + k];
        acc[0][0] += a0x * b4.x; acc[0][1] += a0x * b4.y; acc[0][2] += a0x * b4.z; acc[0][3] += a0x * b4.w;
        acc[1][0] += a1x * b4.x; acc[1][1] += a1x * b4.y; acc[1][2] += a1x * b4.z; acc[1][3] += a1x * b4.w;
        acc[2][0] += a2x * b4.x; acc[2][1] += a2x * b4.y; acc[2][2] += a2x * b4.z; acc[2][3] += a2x * b4.w;
        acc[3][0] += a3x * b4.x; acc[3][1] += a3x * b4.y; acc[3][2] += a3x * b4.z; acc[3][3] += a3x * b4.w;
    }
    float hw4[4];
#pragma unroll
    for (int j = 0; j < 4; ++j) hw4[j] = hw[cc * 4 + j];
#pragma unroll
    for (int i = 0; i < 4; ++i) {
        int gn = tile0 + nc * 4 + i;
        float p = 0.f;
        if (gn < NN) {
            size_t q = (size_t)gn * 64 + cc * 4;
            uint2 v1 = *(const uint2*)&h1[q];
            uint2 v2 = *(const uint2*)&h2[q];
            uint2 v3 = *(const uint2*)&h3[q];
            float m0 = fmaxf(acc[i][0], 0.f);
            float m1 = fmaxf(acc[i][1], 0.f);
            float m2 = fmaxf(acc[i][2], 0.f);
            float m3 = fmaxf(acc[i][3], 0.f);
            m0 = fmaxf(m0, fmaxf(bf2f(v1.x & 0xffffu), fmaxf(bf2f(v2.x & 0xffffu), bf2f(v3.x & 0xffffu))));
            m1 = fmaxf(m1, fmaxf(bf2f(v1.x >> 16), fmaxf(bf2f(v2.x >> 16), bf2f(v3.x >> 16))));
            m2 = fmaxf(m2, fmaxf(bf2f(v1.y & 0xffffu), fmaxf(bf2f(v2.y & 0xffffu), bf2f(v3.y & 0xffffu))));
            m3 = fmaxf(m3, fmaxf(bf2f(v1.y >> 16), fmaxf(bf2f(v2.y >> 16), bf2f(v3.y >> 16))));
            p = m0 * hw4[0] + m1 * hw4[1] + m2 * hw4[2] + m3 * hw4[3];
        }
#pragma unroll
        for (int m = 1; m < 16; m <<= 1) p += __shfl_xor(p, m);
        if (cc == 0 && gn < NN) out[gn] = out[gn] + 0.5f * (p + hbias[0]);
    }
}

extern "C" void kernel_launch(void* const* d_in, const int* in_sizes, int n_in,
                              void* d_out, int out_size, void* d_ws, size_t ws_size,
                              hipStream_t stream) {
    const float* x      = (const float*)d_in[0];
    const float* ew     = (const float*)d_in[1];
    const float* proj_w = (const float*)d_in[2];
    const float* proj_b = (const float*)d_in[3];
    const float* gcn_w  = (const float*)d_in[4];
    const float* w1     = (const float*)d_in[5];
    const float* b1     = (const float*)d_in[6];
    const float* g1     = (const float*)d_in[7];
    const float* be1    = (const float*)d_in[8];
    const float* w2     = (const float*)d_in[9];
    const float* b2     = (const float*)d_in[10];
    const float* g2     = (const float*)d_in[11];
    const float* be2    = (const float*)d_in[12];
    const float* w3     = (const float*)d_in[13];
    const float* b3     = (const float*)d_in[14];
    const float* hw     = (const float*)d_in[15];
    const float* hb     = (const float*)d_in[16];
    const int*   ei     = (const int*)d_in[17];
    float* out = (float*)d_out;

    char* ws = (char*)d_ws;
    size_t off = 0;
    auto alloc = [&](size_t bytes) { size_t o = off; off += (bytes + 255) & ~(size_t)255; return o; };
    unsigned short* h0b = (unsigned short*)(ws + alloc((size_t)NN * 64 * 2));
    unsigned short* hl1 = (unsigned short*)(ws + alloc((size_t)NN * 64 * 2));
    unsigned short* hl2 = (unsigned short*)(ws + alloc((size_t)NN * 64 * 2));
    unsigned short* hl3 = (unsigned short*)(ws + alloc((size_t)NN * 64 * 2));
    float* M       = (float*)(ws + alloc((size_t)4 * 64 * 64 * 4));
    unsigned short* pWt = (unsigned short*)(ws + alloc((size_t)8192 * 2));
    unsigned short* W1t = (unsigned short*)(ws + alloc((size_t)8192 * 2));
    unsigned short* W2t = (unsigned short*)(ws + alloc((size_t)4096 * 2));
    int*   cnt     = (int*)(ws + alloc((size_t)NBUK * 4));
    int*   rp      = (int*)(ws + alloc((size_t)NBUK * 65 * 4));
    int2*  ep      = (int2*)(ws + alloc((size_t)NBUK * STRIDE * 8 + 512));
    int2*  ep2     = (int2*)(ws + alloc((size_t)NBUK * STRIDE * 8 + 512));   // +512B slack for window overread

    const int* srcv = ei;
    const int* dstv = ei + NE;

    k_wprep<<<80, 256, 0, stream>>>(proj_w, w1, w2, pWt, W1t, W2t, cnt);

    // front: MFMA projmlp || bscatter || mprep  (theta_l = log(1/(l+1) + 1))
    k_front<<<NBUK + NBLK + 64, 256, 0, stream>>>(x, pWt, proj_b, W1t, b1, g1, be1,
        W2t, b2, g2, be2, w3, b3, h0b, out, srcv, dstv, ew, cnt, ep, gcn_w, M,
        make_float4(0.69314718055994531f, 0.40546510810816438f,
                    0.28768207245178085f, 0.22314355131420976f));

    k_layer1<<<NBUK, 256, 0, stream>>>(ep, cnt, ep2, rp, h0b, M + 0 * 4096, hl1);
    k_layer<<<NBUK, 256, 0, stream>>>(ep2, rp, hl1, h0b, M + 1 * 4096, hl2);
    k_layer<<<NBUK, 256, 0, stream>>>(ep2, rp, hl2, h0b, M + 2 * 4096, hl3);
    k_layer4<<<NBUK, 256, 0, stream>>>(ep2, rp, hl3, h0b, M + 3 * 4096,
                                       hl1, hl2, hl3, hw, hb, out);
}